// Round 2
// baseline (313.916 us; speedup 1.0000x reference)
//
#include <hip/hip_runtime.h>

typedef __bf16 bf16x8 __attribute__((ext_vector_type(8)));
typedef float floatx16 __attribute__((ext_vector_type(16)));
typedef unsigned short us8 __attribute__((ext_vector_type(8)));

__device__ __forceinline__ unsigned short f2bf(float f) {
    union { float f; unsigned int u; } a;
    a.f = f;
    unsigned int u = a.u;
    return (unsigned short)((u + 0x7FFFu + ((u >> 16) & 1u)) >> 16);  // RNE
}

__device__ __forceinline__ void async_copy16(const void* g, void* l) {
    __builtin_amdgcn_global_load_lds(
        (const __attribute__((address_space(1))) unsigned int*)g,
        (__attribute__((address_space(3))) unsigned int*)l,
        16, 0, 0);
}

__device__ __forceinline__ float sigmoidf_fast(float x) {
    return 1.f / (1.f + __expf(-x));
}
__device__ __forceinline__ float tanhf_fast(float x) {
    return 1.f - 2.f / (__expf(2.f * x) + 1.f);   // exact at +-inf
}

// Prep: [x|h] -> Abf [8192,2048] bf16 (identity rows) and [Wx|Wh] -> Wbf
// [4096,2048] bf16 with row permutation
//   out row n' = hg*64 + gate*16 + hl  <-  src row gate*1024 + hg*16 + hl
// (h = hg*16 + hl). With 32x32 MFMA N-frags (32 cols = 2 gates), lanes l and
// l^16 hold complementary gate pairs of the SAME h -> epilogue exchange is a
// single shfl_xor(16), no LDS.
__global__ __launch_bounds__(256) void prep_cat(
        const float* __restrict__ x, const float* __restrict__ h,
        const float* __restrict__ Wx, const float* __restrict__ Wh,
        unsigned short* __restrict__ Abf, unsigned short* __restrict__ Wbf) {
    int T = blockIdx.x * 256 + threadIdx.x;
    size_t e;
    const float* a;
    const float* b;
    unsigned short* o;
    size_t srow;
    if (T < 2097152) {                       // A: 16,777,216 elems / 8
        e = (size_t)T * 8;
        a = x; b = h; o = Abf;
        srow = e >> 11;
    } else {                                 // W: 8,388,608 elems / 8
        e = (size_t)(T - 2097152) * 8;
        a = Wx; b = Wh; o = Wbf;
        int m = (int)(e >> 11);              // permuted (output) row
        int hg = m >> 6, gate = (m >> 4) & 3, hl = m & 15;
        srow = (size_t)(gate * 1024 + hg * 16 + hl);
    }
    int k = (int)(e & 2047);
    const float* src = (k < 1024) ? (a + srow * 1024 + k)
                                  : (b + srow * 1024 + (k - 1024));
    float4 v0 = ((const float4*)src)[0];
    float4 v1 = ((const float4*)src)[1];
    us8 u;
    u[0] = f2bf(v0.x); u[1] = f2bf(v0.y); u[2] = f2bf(v0.z); u[3] = f2bf(v0.w);
    u[4] = f2bf(v1.x); u[5] = f2bf(v1.y); u[6] = f2bf(v1.z); u[7] = f2bf(v1.w);
    *(us8*)(o + e) = u;
}

// Fused GEMM + LSTM, 256x256 tile, BK=64, 8 waves (2M x 4N), 32x32x16 MFMA.
// Software-pipelined: each phase issues ds_reads for slice s+1 (double-
// buffered register frags) then MFMAs slice s -> compiler emits counted
// lgkmcnt, LDS drain hides under MFMA. Only 2 barriers per K-tile:
//   (1) after all reads of cur B done, before staging B(t+2) into cur.B
//   (2) tile boundary with counted vmcnt(4) (A(t+1)+B(t+1) landed,
//       B(t+2) still in flight -- never drain to 0 mid-loop).
#define NT 32   // K / 64

__global__ __launch_bounds__(512) void gemm_lstm(
        const unsigned short* __restrict__ A,     // [8192,2048] bf16
        const unsigned short* __restrict__ W,     // [4096,2048] bf16, gate-per-16 rows
        const float* __restrict__ bx, const float* __restrict__ bh,
        const float* __restrict__ c1,             // [8192,1024] f32
        float* __restrict__ out) {                // h_new [8192,1024] then c
    // 2 buffers x (A 256x64 + B 256x64) bf16 = 128KB.
    // Half-tile = 128 rows x 128B, 16B chunk swizzle: phys = logical ^ (row&7).
    __shared__ __align__(16) char smem[131072];

    const int tid = threadIdx.x;
    const int lane = tid & 63;
    const int wave = tid >> 6;
    const int wm = wave >> 2;        // 0..1 -> M half (128 rows)
    const int wn = wave & 3;         // 0..3 -> 64-col span
    const int l31 = lane & 31;
    const int l15 = lane & 15;
    const int h5 = lane >> 5;
    const int L7 = lane & 7;

    // XCD-bijective swizzle (512 % 8 == 0).
    int bid = (int)blockIdx.x;
    int swz = (bid & 7) * 64 + (bid >> 3);
    const int tileM = (swz & 31) * 256;
    const int tileN = (swz >> 5) * 256;

    // Stage one 16KB half-tile: 512 thr x 2 x 16B, LDS dest linear,
    // swizzle applied on the GLOBAL source.
    auto stage = [&](const unsigned short* __restrict__ G, int grow0, int kt,
                     char* ldsbase) {
#pragma unroll
        for (int r = 0; r < 2; ++r) {
            int rh = r * 64 + (tid >> 3);
            int kc = (tid & 7) ^ (rh & 7);
            const unsigned short* src = G + (size_t)(grow0 + rh) * 2048 + kt + kc * 8;
            async_copy16(src, ldsbase + r * 8192 + wave * 1024);
        }
    };

    char* b0 = smem;
    char* b1 = smem + 65536;

    // Prologue: A(0), B(0) -> b0; B(1) -> b1.B; A(1) staged inside t=0.
    stage(A, tileM,        0, b0);
    stage(A, tileM + 128,  0, b0 + 16384);
    stage(W, tileN,        0, b0 + 32768);
    stage(W, tileN + 128,  0, b0 + 49152);
    stage(W, tileN,       64, b1 + 32768);
    stage(W, tileN + 128, 64, b1 + 49152);
    asm volatile("s_waitcnt vmcnt(4)" ::: "memory");
    __builtin_amdgcn_s_barrier();
    __builtin_amdgcn_sched_barrier(0);

    // Per-lane swizzled chunk byte-offsets per 16-k slice:
    // logical chunk = 2*s + h5, phys = logical ^ (row&7) = logical ^ L7.
    int cph[4];
#pragma unroll
    for (int s = 0; s < 4; ++s) cph[s] = (((2 * s + h5) ^ L7) << 4);

    floatx16 acc[4][2] = {};
    bf16x8 fA[2][4];
    bf16x8 fB[2][2];

    // Initial reads: slice 0 of tile 0 from b0.
    {
        const char* Ar = b0 + wm * 16384 + l31 * 128 + cph[0];
        const char* Br = b0 + 32768 + wn * 8192 + l31 * 128 + cph[0];
#pragma unroll
        for (int mi = 0; mi < 4; ++mi) fA[0][mi] = *(const bf16x8*)(Ar + mi * 4096);
#pragma unroll
        for (int nj = 0; nj < 2; ++nj) fB[0][nj] = *(const bf16x8*)(Br + nj * 4096);
    }

    for (int t = 0; t < NT; ++t) {
        const int cb = (t & 1) << 16;
        const int nb = ((t + 1) & 1) << 16;
        const char* Ab = smem + cb + wm * 16384 + l31 * 128;
        const char* Bb = smem + cb + 32768 + wn * 8192 + l31 * 128;
#pragma unroll
        for (int s = 0; s < 4; ++s) {
            if (s == 0 && t + 1 < NT) stage(A, tileM,       (t + 1) * 64, smem + nb);
            if (s == 1 && t + 1 < NT) stage(A, tileM + 128, (t + 1) * 64, smem + nb + 16384);
            if (s == 3) {
                // all my reads of cur (incl. slice-3 B) complete, then fence
                asm volatile("s_waitcnt lgkmcnt(0)" ::: "memory");
                __builtin_amdgcn_sched_barrier(0);
                __builtin_amdgcn_s_barrier();
                __builtin_amdgcn_sched_barrier(0);
                if (t + 2 < NT) {
                    stage(W, tileN,       (t + 2) * 64, smem + cb + 32768);
                    stage(W, tileN + 128, (t + 2) * 64, smem + cb + 49152);
                }
            }
            if (s < 3) {
                const char* Ar = Ab + cph[s + 1];
                const char* Br = Bb + cph[s + 1];
#pragma unroll
                for (int mi = 0; mi < 4; ++mi)
                    fA[(s + 1) & 1][mi] = *(const bf16x8*)(Ar + mi * 4096);
#pragma unroll
                for (int nj = 0; nj < 2; ++nj)
                    fB[(s + 1) & 1][nj] = *(const bf16x8*)(Br + nj * 4096);
            }
            __builtin_amdgcn_sched_barrier(0);
            __builtin_amdgcn_s_setprio(1);
#pragma unroll
            for (int mi = 0; mi < 4; ++mi)
#pragma unroll
                for (int nj = 0; nj < 2; ++nj)
                    acc[mi][nj] = __builtin_amdgcn_mfma_f32_32x32x16_bf16(
                        fA[s & 1][mi], fB[s & 1][nj], acc[mi][nj], 0, 0, 0);
            __builtin_amdgcn_s_setprio(0);
            if (s == 3) {
                if (t + 2 < NT) {
                    asm volatile("s_waitcnt vmcnt(4)" ::: "memory");
                } else if (t + 1 < NT) {
                    asm volatile("s_waitcnt vmcnt(0)" ::: "memory");
                }
                __builtin_amdgcn_sched_barrier(0);
                __builtin_amdgcn_s_barrier();
                __builtin_amdgcn_sched_barrier(0);
                if (t + 1 < NT) {
                    const char* Ar = smem + nb + wm * 16384 + l31 * 128 + cph[0];
                    const char* Br = smem + nb + 32768 + wn * 8192 + l31 * 128 + cph[0];
#pragma unroll
                    for (int mi = 0; mi < 4; ++mi)
                        fA[0][mi] = *(const bf16x8*)(Ar + mi * 4096);
#pragma unroll
                    for (int nj = 0; nj < 2; ++nj)
                        fB[0][nj] = *(const bf16x8*)(Br + nj * 4096);
                }
            }
        }
    }

    // ---- epilogue ----
    // 32x32 C/D map: col = lane&31, row = (v&3) + 8*(v>>2) + 4*(lane>>5).
    // N-frag nj: col c -> gate = nj*2 + (c>>4), hl = c&15.  Lanes l / l^16:
    // same h, gates {i,o} vs {f,c}.  shfl_xor(16) swaps; each lane then
    // processes v-half matching its group (lo: v 0..7, hi: v 8..15).
    const int hidx = (tileN >> 2) + wn * 16 + l15;   // global h in [0,1024)
    const int hi4 = (lane >> 4) & 1;
    const float bi  = bx[hidx]        + bh[hidx];
    const float bff = bx[1024 + hidx] + bh[1024 + hidx];
    const float bo  = bx[2048 + hidx] + bh[2048 + hidx];
    const float bc  = bx[3072 + hidx] + bh[3072 + hidx];
    const int rb = wm * 128 + hi4 * 16 + h5 * 4;

#pragma unroll
    for (int mi = 0; mi < 4; ++mi) {
        float s0[16], s1[16];
#pragma unroll
        for (int v = 0; v < 16; ++v) {
            s0[v] = __shfl_xor(acc[mi][0][v], 16);
            s1[v] = __shfl_xor(acc[mi][1][v], 16);
        }
#pragma unroll
        for (int u = 0; u < 8; ++u) {
            float a0l = acc[mi][0][u], a0h = acc[mi][0][u + 8];
            float a1l = acc[mi][1][u], a1h = acc[mi][1][u + 8];
            float gi = (hi4 ? s0[u + 8] : a0l) + bi;
            float gf = (hi4 ? a0h       : s0[u]) + bff;
            float go = (hi4 ? s1[u + 8] : a1l) + bo;
            float gc = (hi4 ? a1h       : s1[u]) + bc;
            int m = rb + mi * 32 + (u & 3) + 8 * (u >> 2);
            size_t goff = (size_t)(tileM + m) * 1024 + hidx;
            float c1v = c1[goff];
            float ii = sigmoidf_fast(gi);
            float ff = sigmoidf_fast(gf);
            float oo = sigmoidf_fast(go);
            float cb_ = tanhf_fast(gc);
            float cc = sigmoidf_fast(ff * c1v + ii * cb_);   // reference quirk
            float hn = tanhf_fast(cc) * oo;
            out[goff] = hn;
            out[8388608 + goff] = cc;
        }
    }
}

extern "C" void kernel_launch(void* const* d_in, const int* in_sizes, int n_in,
                              void* d_out, int out_size, void* d_ws, size_t ws_size,
                              hipStream_t stream) {
    const float* x  = (const float*)d_in[0];
    const float* h  = (const float*)d_in[1];
    const float* c1 = (const float*)d_in[2];
    const float* Wx = (const float*)d_in[3];
    const float* bx = (const float*)d_in[4];
    const float* Wh = (const float*)d_in[5];
    const float* bh = (const float*)d_in[6];
    float* out = (float*)d_out;

    char* ws = (char*)d_ws;
    unsigned short* Abf = (unsigned short*)(ws);                // 33,554,432 B
    unsigned short* Wbf = (unsigned short*)(ws + 33554432);     // 16,777,216 B

    prep_cat<<<12288, 256, 0, stream>>>(x, h, Wx, Wh, Abf, Wbf);
    gemm_lstm<<<512, 512, 0, stream>>>(Abf, Wbf, bx, bh, c1, out);
}

// Round 3
// 310.482 us; speedup vs baseline: 1.0111x; 1.0111x over previous
//
#include <hip/hip_runtime.h>

typedef __bf16 bf16x8 __attribute__((ext_vector_type(8)));
typedef float floatx16 __attribute__((ext_vector_type(16)));
typedef unsigned short us8 __attribute__((ext_vector_type(8)));

__device__ __forceinline__ unsigned short f2bf(float f) {
    union { float f; unsigned int u; } a;
    a.f = f;
    unsigned int u = a.u;
    return (unsigned short)((u + 0x7FFFu + ((u >> 16) & 1u)) >> 16);  // RNE
}

__device__ __forceinline__ void async_copy16(const void* g, void* l) {
    __builtin_amdgcn_global_load_lds(
        (const __attribute__((address_space(1))) unsigned int*)g,
        (__attribute__((address_space(3))) unsigned int*)l,
        16, 0, 0);
}

__device__ __forceinline__ float sigmoidf_fast(float x) {
    return 1.f / (1.f + __expf(-x));
}
__device__ __forceinline__ float tanhf_fast(float x) {
    return 1.f - 2.f / (__expf(2.f * x) + 1.f);   // exact at +-inf
}

// Prep: [x|h] -> Abf [8192,2048] bf16 (identity rows) and [Wx|Wh] -> Wbf
// [4096,2048] bf16 with row permutation
//   out row n' = hg*64 + gate*16 + hl  <-  src row gate*1024 + hg*16 + hl
// (h = hg*16 + hl). With 32x32 MFMA N-frags (32 cols = 2 gates), lanes l and
// l^16 hold complementary gate pairs of the SAME h -> epilogue exchange is a
// single shfl_xor(16), no LDS.
__global__ __launch_bounds__(256) void prep_cat(
        const float* __restrict__ x, const float* __restrict__ h,
        const float* __restrict__ Wx, const float* __restrict__ Wh,
        unsigned short* __restrict__ Abf, unsigned short* __restrict__ Wbf) {
    int T = blockIdx.x * 256 + threadIdx.x;
    size_t e;
    const float* a;
    const float* b;
    unsigned short* o;
    size_t srow;
    if (T < 2097152) {                       // A: 16,777,216 elems / 8
        e = (size_t)T * 8;
        a = x; b = h; o = Abf;
        srow = e >> 11;
    } else {                                 // W: 8,388,608 elems / 8
        e = (size_t)(T - 2097152) * 8;
        a = Wx; b = Wh; o = Wbf;
        int m = (int)(e >> 11);              // permuted (output) row
        int hg = m >> 6, gate = (m >> 4) & 3, hl = m & 15;
        srow = (size_t)(gate * 1024 + hg * 16 + hl);
    }
    int k = (int)(e & 2047);
    const float* src = (k < 1024) ? (a + srow * 1024 + k)
                                  : (b + srow * 1024 + (k - 1024));
    float4 v0 = ((const float4*)src)[0];
    float4 v1 = ((const float4*)src)[1];
    us8 u;
    u[0] = f2bf(v0.x); u[1] = f2bf(v0.y); u[2] = f2bf(v0.z); u[3] = f2bf(v0.w);
    u[4] = f2bf(v1.x); u[5] = f2bf(v1.y); u[6] = f2bf(v1.z); u[7] = f2bf(v1.w);
    *(us8*)(o + e) = u;
}

// Fused GEMM + LSTM, 256x256 tile, BK=64, 8 waves (2M x 4N), 32x32x16 MFMA.
// Software-pipelined: each phase issues ds_reads for slice s+1 (double-
// buffered register frags) then MFMAs slice s (counted lgkmcnt from the
// compiler hides LDS latency under MFMA). 2 barriers per K-tile, counted
// vmcnt(4) at the boundary (never drain to 0 mid-loop).
//
// LDS bank swizzle (both-sides rule): at 128B row stride, row*128 = 0 mod
// 32 banks, so the bank index depends only on the 16B chunk.  Swizzle
//   phys_chunk = logical ^ (row&7) ^ ((row>>2)&4)
// injects row bits 0-2 AND bit 4 into the chunk so any 8/16-lane LDS phase
// group covers all 32 banks evenly (round-2's version omitted bit 4 ->
// 4-way conflict, 1.26e7 extra cycles).
#define NT 32   // K / 64

__global__ __launch_bounds__(512) void gemm_lstm(
        const unsigned short* __restrict__ A,     // [8192,2048] bf16
        const unsigned short* __restrict__ W,     // [4096,2048] bf16, gate-per-16 rows
        const float* __restrict__ bx, const float* __restrict__ bh,
        const float* __restrict__ c1,             // [8192,1024] f32
        float* __restrict__ out) {                // h_new [8192,1024] then c
    // 2 buffers x (A 256x64 + B 256x64) bf16 = 128KB.
    __shared__ __align__(16) char smem[131072];

    const int tid = threadIdx.x;
    const int lane = tid & 63;
    const int wave = tid >> 6;
    const int wm = wave >> 2;        // 0..1 -> M half (128 rows)
    const int wn = wave & 3;         // 0..3 -> 64-col span
    const int l31 = lane & 31;
    const int l15 = lane & 15;
    const int h5 = lane >> 5;
    const int L7 = lane & 7;

    // XCD swizzle, 8x8 chunk per XCD: XCD x covers M-tiles [cm*8, cm*8+8),
    // N-tiles [cn*8, cn*8+8)  (cm = x>>1, cn = x&1).  Per-XCD working set
    // 8 A-panels + 8 W-panels (16MB) vs 32+2 before -> less HBM re-fetch.
    int bid = (int)blockIdx.x;
    int x8 = bid & 7;
    int q = bid >> 3;                 // 0..63
    const int tileM = (((x8 >> 1) * 8) + (q & 7)) * 256;
    const int tileN = (((x8 & 1) * 8) + (q >> 3)) * 256;

    // Stage one 16KB half-tile: 512 thr x 2 x 16B, LDS dest linear,
    // swizzle applied on the GLOBAL source (inverse == forward, involution).
    auto stage = [&](const unsigned short* __restrict__ G, int grow0, int kt,
                     char* ldsbase) {
#pragma unroll
        for (int r = 0; r < 2; ++r) {
            int rh = r * 64 + (tid >> 3);
            int kc = (tid & 7) ^ (rh & 7) ^ ((rh >> 2) & 4);
            const unsigned short* src = G + (size_t)(grow0 + rh) * 2048 + kt + kc * 8;
            async_copy16(src, ldsbase + r * 8192 + wave * 1024);
        }
    };

    char* b0 = smem;
    char* b1 = smem + 65536;

    // Prologue: A(0), B(0) -> b0; B(1) -> b1.B; A(1) staged inside t=0.
    stage(A, tileM,        0, b0);
    stage(A, tileM + 128,  0, b0 + 16384);
    stage(W, tileN,        0, b0 + 32768);
    stage(W, tileN + 128,  0, b0 + 49152);
    stage(W, tileN,       64, b1 + 32768);
    stage(W, tileN + 128, 64, b1 + 49152);
    asm volatile("s_waitcnt vmcnt(4)" ::: "memory");
    __builtin_amdgcn_s_barrier();
    __builtin_amdgcn_sched_barrier(0);

    // Per-lane swizzled chunk byte-offsets per 16-k slice.  Reader row =
    // l31 (+32*mi, which preserves row&7 and row&16): logical chunk =
    // 2s + h5, phys = logical ^ (l31&7) ^ ((l31>>2)&4).
    int cph[4];
#pragma unroll
    for (int s = 0; s < 4; ++s)
        cph[s] = (((2 * s + h5) ^ L7 ^ ((l31 >> 2) & 4)) << 4);

    floatx16 acc[4][2] = {};
    bf16x8 fA[2][4];
    bf16x8 fB[2][2];

    // Initial reads: slice 0 of tile 0 from b0.
    {
        const char* Ar = b0 + wm * 16384 + l31 * 128 + cph[0];
        const char* Br = b0 + 32768 + wn * 8192 + l31 * 128 + cph[0];
#pragma unroll
        for (int mi = 0; mi < 4; ++mi) fA[0][mi] = *(const bf16x8*)(Ar + mi * 4096);
#pragma unroll
        for (int nj = 0; nj < 2; ++nj) fB[0][nj] = *(const bf16x8*)(Br + nj * 4096);
    }

    for (int t = 0; t < NT; ++t) {
        const int cb = (t & 1) << 16;
        const int nb = ((t + 1) & 1) << 16;
        const char* Ab = smem + cb + wm * 16384 + l31 * 128;
        const char* Bb = smem + cb + 32768 + wn * 8192 + l31 * 128;
#pragma unroll
        for (int s = 0; s < 4; ++s) {
            if (s == 0 && t + 1 < NT) stage(A, tileM,       (t + 1) * 64, smem + nb);
            if (s == 1 && t + 1 < NT) stage(A, tileM + 128, (t + 1) * 64, smem + nb + 16384);
            if (s == 3) {
                // all my reads of cur (incl. slice-3 B) complete, then fence
                asm volatile("s_waitcnt lgkmcnt(0)" ::: "memory");
                __builtin_amdgcn_sched_barrier(0);
                __builtin_amdgcn_s_barrier();
                __builtin_amdgcn_sched_barrier(0);
                if (t + 2 < NT) {
                    stage(W, tileN,       (t + 2) * 64, smem + cb + 32768);
                    stage(W, tileN + 128, (t + 2) * 64, smem + cb + 49152);
                }
            }
            if (s < 3) {
                const char* Ar = Ab + cph[s + 1];
                const char* Br = Bb + cph[s + 1];
#pragma unroll
                for (int mi = 0; mi < 4; ++mi)
                    fA[(s + 1) & 1][mi] = *(const bf16x8*)(Ar + mi * 4096);
#pragma unroll
                for (int nj = 0; nj < 2; ++nj)
                    fB[(s + 1) & 1][nj] = *(const bf16x8*)(Br + nj * 4096);
            }
            __builtin_amdgcn_sched_barrier(0);
            __builtin_amdgcn_s_setprio(1);
#pragma unroll
            for (int mi = 0; mi < 4; ++mi)
#pragma unroll
                for (int nj = 0; nj < 2; ++nj)
                    acc[mi][nj] = __builtin_amdgcn_mfma_f32_32x32x16_bf16(
                        fA[s & 1][mi], fB[s & 1][nj], acc[mi][nj], 0, 0, 0);
            __builtin_amdgcn_s_setprio(0);
            if (s == 3) {
                if (t + 2 < NT) {
                    asm volatile("s_waitcnt vmcnt(4)" ::: "memory");
                } else if (t + 1 < NT) {
                    asm volatile("s_waitcnt vmcnt(0)" ::: "memory");
                }
                __builtin_amdgcn_sched_barrier(0);
                __builtin_amdgcn_s_barrier();
                __builtin_amdgcn_sched_barrier(0);
                if (t + 1 < NT) {
                    const char* Ar = smem + nb + wm * 16384 + l31 * 128 + cph[0];
                    const char* Br = smem + nb + 32768 + wn * 8192 + l31 * 128 + cph[0];
#pragma unroll
                    for (int mi = 0; mi < 4; ++mi)
                        fA[0][mi] = *(const bf16x8*)(Ar + mi * 4096);
#pragma unroll
                    for (int nj = 0; nj < 2; ++nj)
                        fB[0][nj] = *(const bf16x8*)(Br + nj * 4096);
                }
            }
        }
    }

    // ---- epilogue ----
    // 32x32 C/D map: col = lane&31, row = (v&3) + 8*(v>>2) + 4*(lane>>5).
    // N-frag nj: col c -> gate = nj*2 + (c>>4), hl = c&15.  Lanes l / l^16:
    // same h, gates {i,o} vs {f,c}.  shfl_xor(16) swaps; each lane then
    // processes v-half matching its group (lo: v 0..7, hi: v 8..15).
    const int hidx = (tileN >> 2) + wn * 16 + l15;   // global h in [0,1024)
    const int hi4 = (lane >> 4) & 1;
    const float bi  = bx[hidx]        + bh[hidx];
    const float bff = bx[1024 + hidx] + bh[1024 + hidx];
    const float bo  = bx[2048 + hidx] + bh[2048 + hidx];
    const float bc  = bx[3072 + hidx] + bh[3072 + hidx];
    const int rb = wm * 128 + hi4 * 16 + h5 * 4;

#pragma unroll
    for (int mi = 0; mi < 4; ++mi) {
        float s0[16], s1[16];
#pragma unroll
        for (int v = 0; v < 16; ++v) {
            s0[v] = __shfl_xor(acc[mi][0][v], 16);
            s1[v] = __shfl_xor(acc[mi][1][v], 16);
        }
#pragma unroll
        for (int u = 0; u < 8; ++u) {
            float a0l = acc[mi][0][u], a0h = acc[mi][0][u + 8];
            float a1l = acc[mi][1][u], a1h = acc[mi][1][u + 8];
            float gi = (hi4 ? s0[u + 8] : a0l) + bi;
            float gf = (hi4 ? a0h       : s0[u]) + bff;
            float go = (hi4 ? s1[u + 8] : a1l) + bo;
            float gc = (hi4 ? a1h       : s1[u]) + bc;
            int m = rb + mi * 32 + (u & 3) + 8 * (u >> 2);
            size_t goff = (size_t)(tileM + m) * 1024 + hidx;
            float c1v = c1[goff];
            float ii = sigmoidf_fast(gi);
            float ff = sigmoidf_fast(gf);
            float oo = sigmoidf_fast(go);
            float cb_ = tanhf_fast(gc);
            float cc = sigmoidf_fast(ff * c1v + ii * cb_);   // reference quirk
            float hn = tanhf_fast(cc) * oo;
            out[goff] = hn;
            out[8388608 + goff] = cc;
        }
    }
}

extern "C" void kernel_launch(void* const* d_in, const int* in_sizes, int n_in,
                              void* d_out, int out_size, void* d_ws, size_t ws_size,
                              hipStream_t stream) {
    const float* x  = (const float*)d_in[0];
    const float* h  = (const float*)d_in[1];
    const float* c1 = (const float*)d_in[2];
    const float* Wx = (const float*)d_in[3];
    const float* bx = (const float*)d_in[4];
    const float* Wh = (const float*)d_in[5];
    const float* bh = (const float*)d_in[6];
    float* out = (float*)d_out;

    char* ws = (char*)d_ws;
    unsigned short* Abf = (unsigned short*)(ws);                // 33,554,432 B
    unsigned short* Wbf = (unsigned short*)(ws + 33554432);     // 16,777,216 B

    prep_cat<<<12288, 256, 0, stream>>>(x, h, Wx, Wh, Abf, Wbf);
    gemm_lstm<<<512, 512, 0, stream>>>(Abf, Wbf, bx, bh, c1, out);
}

// Round 4
// 303.583 us; speedup vs baseline: 1.0340x; 1.0227x over previous
//
#include <hip/hip_runtime.h>

typedef __bf16 bf16x8 __attribute__((ext_vector_type(8)));
typedef float floatx4 __attribute__((ext_vector_type(4)));
typedef unsigned short us8 __attribute__((ext_vector_type(8)));

__device__ __forceinline__ unsigned short f2bf(float f) {
    union { float f; unsigned int u; } a;
    a.f = f;
    unsigned int u = a.u;
    return (unsigned short)((u + 0x7FFFu + ((u >> 16) & 1u)) >> 16);  // RNE
}

__device__ __forceinline__ void async_copy16(const void* g, void* l) {
    __builtin_amdgcn_global_load_lds(
        (const __attribute__((address_space(1))) unsigned int*)g,
        (__attribute__((address_space(3))) unsigned int*)l,
        16, 0, 0);
}

__device__ __forceinline__ float sigmoidf_fast(float x) {
    return 1.f / (1.f + __expf(-x));
}
__device__ __forceinline__ float tanhf_fast(float x) {
    return 1.f - 2.f / (__expf(2.f * x) + 1.f);   // exact at +-inf
}

// Prep: [x|h] -> Abf [8192,2048] bf16 (identity rows) and [Wx|Wh] -> Wbf
// [4096,2048] bf16 with row permutation
//   out row n' = hg*64 + gate*16 + hl  <-  src row gate*1024 + hg*16 + hl
// (h = hg*16 + hl). With 16x16 MFMA N-frags (16 cols), each N-frag is
// exactly ONE gate: lane l15 holds all 4 gates of its h across acc[mi][0..3]
// -> epilogue is pure register math, no exchange at all.
__global__ __launch_bounds__(256) void prep_cat(
        const float* __restrict__ x, const float* __restrict__ h,
        const float* __restrict__ Wx, const float* __restrict__ Wh,
        unsigned short* __restrict__ Abf, unsigned short* __restrict__ Wbf) {
    int T = blockIdx.x * 256 + threadIdx.x;
    size_t e;
    const float* a;
    const float* b;
    unsigned short* o;
    size_t srow;
    if (T < 2097152) {                       // A: 16,777,216 elems / 8
        e = (size_t)T * 8;
        a = x; b = h; o = Abf;
        srow = e >> 11;
    } else {                                 // W: 8,388,608 elems / 8
        e = (size_t)(T - 2097152) * 8;
        a = Wx; b = Wh; o = Wbf;
        int m = (int)(e >> 11);              // permuted (output) row
        int hg = m >> 6, gate = (m >> 4) & 3, hl = m & 15;
        srow = (size_t)(gate * 1024 + hg * 16 + hl);
    }
    int k = (int)(e & 2047);
    const float* src = (k < 1024) ? (a + srow * 1024 + k)
                                  : (b + srow * 1024 + (k - 1024));
    float4 v0 = ((const float4*)src)[0];
    float4 v1 = ((const float4*)src)[1];
    us8 u;
    u[0] = f2bf(v0.x); u[1] = f2bf(v0.y); u[2] = f2bf(v0.z); u[3] = f2bf(v0.w);
    u[4] = f2bf(v1.x); u[5] = f2bf(v1.y); u[6] = f2bf(v1.z); u[7] = f2bf(v1.w);
    *(us8*)(o + e) = u;
}

// Fused GEMM + LSTM, m201 8-phase template port: 256x256 tile, BK=64,
// 8 waves (2M x 4N), 16x16x32 MFMA.  Per K-tile: 4 phases, each =
//   { ds_read subtile (4-12 b128) ; stage 1 half-tile (2 x gload_lds) ;
//     barrier ; lgkmcnt(0) ; sched_barrier ; setprio(1) ; 16 MFMA ;
//     setprio(0) ; barrier }
// Depth-1 double buffer; boundary vmcnt(0) whose loads are 1-4 phases old.
// LDS swizzle (both-sides): phys_chunk = logical ^ (row&7) ^ ((row>>2)&4),
// applied at stage (global source) and ds_read.  Epilogue register-only.
#define NT 32   // K / 64

__global__ __launch_bounds__(512) void gemm_lstm(
        const unsigned short* __restrict__ A,     // [8192,2048] bf16
        const unsigned short* __restrict__ W,     // [4096,2048] bf16, gate-per-16 rows
        const float* __restrict__ bx, const float* __restrict__ bh,
        const float* __restrict__ c1,             // [8192,1024] f32
        float* __restrict__ out) {                // h_new [8192,1024] then c
    // 2 buffers x (A 256x64 + B 256x64) bf16 = 128KB.
    __shared__ __align__(16) char smem[131072];

    const int tid = threadIdx.x;
    const int lane = tid & 63;
    const int wave = tid >> 6;
    const int wm = wave >> 2;        // 0..1 -> M half (128 rows)
    const int wn = wave & 3;         // 0..3 -> 64-col span (= 1 h-group x 4 gates)
    const int l15 = lane & 15;
    const int quad = lane >> 4;      // 0..3
    const int L7 = l15 & 7;

    // XCD swizzle, 8x8 tile chunk per XCD (FETCH 287->115MB in r3; keep).
    int bid = (int)blockIdx.x;
    int x8 = bid & 7;
    int q = bid >> 3;                 // 0..63
    const int tileM = (((x8 >> 1) * 8) + (q & 7)) * 256;
    const int tileN = (((x8 & 1) * 8) + (q >> 3)) * 256;

    // Stage one 16KB half-tile (128 rows x 128B): 512 thr x 2 x 16B, LDS
    // dest linear, swizzle applied on the GLOBAL source (involution).
    auto stage = [&](const unsigned short* __restrict__ G, int grow0, int kt,
                     char* ldsbase) {
#pragma unroll
        for (int r = 0; r < 2; ++r) {
            int rh = r * 64 + (tid >> 3);
            int kc = (tid & 7) ^ (rh & 7) ^ ((rh >> 2) & 4);
            const unsigned short* src = G + (size_t)(grow0 + rh) * 2048 + kt + kc * 8;
            async_copy16(src, ldsbase + r * 8192 + wave * 1024);
        }
    };

    char* b0 = smem;

    // Prologue: full tile 0 -> b0.
    stage(A, tileM,        0, b0);
    stage(A, tileM + 128,  0, b0 + 16384);
    stage(W, tileN,        0, b0 + 32768);
    stage(W, tileN + 128,  0, b0 + 49152);
    asm volatile("s_waitcnt vmcnt(0)" ::: "memory");
    __builtin_amdgcn_s_barrier();
    __builtin_amdgcn_sched_barrier(0);

    // Per-lane read offsets.  16x16x32 frag at frag-row-base r0 (mult of 16,
    // parity p = (r0>>4)&1): lane reads row r0+l15, logical chunk ks*4+quad,
    // phys = logical ^ (l15&7) ^ (p*4).  co[p][ks] folds in l15*128.
    int co[2][2];
#pragma unroll
    for (int p = 0; p < 2; ++p)
#pragma unroll
        for (int ks = 0; ks < 2; ++ks)
            co[p][ks] = l15 * 128 + ((((ks * 4 + quad) ^ L7 ^ (p * 4))) << 4);

    floatx4 acc[8][4] = {};
    bf16x8 fA[4][2];   // quadrant qm=0 A frags
    bf16x8 fD[4][2];   // quadrant qm=1 A frags
    bf16x8 fB[2][2];   // qn=0 B frags (gates 0,1)
    bf16x8 fC[2][2];   // qn=1 B frags (gates 2,3)

    for (int t = 0; t < NT; ++t) {
        char* cur = smem + (t & 1) * 65536;
        char* nxt = smem + ((t + 1) & 1) * 65536;
        const char* Ab = cur + wm * 16384;              // wave's A half (128 rows)
        const char* Bb = cur + 32768 + wn * 8192;       // wave's B span (64 rows)
        const int kn = (t + 1) * 64;

        // ---------- phase 1: quadrant (qm0, qn0) ----------
#pragma unroll
        for (int mf = 0; mf < 4; ++mf)
#pragma unroll
            for (int ks = 0; ks < 2; ++ks)
                fA[mf][ks] = *(const bf16x8*)(Ab + mf * 2048 + co[mf & 1][ks]);
#pragma unroll
        for (int nf = 0; nf < 2; ++nf)
#pragma unroll
            for (int ks = 0; ks < 2; ++ks)
                fB[nf][ks] = *(const bf16x8*)(Bb + nf * 2048 + co[nf & 1][ks]);
        if (t + 1 < NT) stage(A, tileM, kn, nxt);
        asm volatile("s_waitcnt lgkmcnt(8)" ::: "memory");
        __builtin_amdgcn_s_barrier();
        asm volatile("s_waitcnt lgkmcnt(0)" ::: "memory");
        __builtin_amdgcn_sched_barrier(0);
        __builtin_amdgcn_s_setprio(1);
#pragma unroll
        for (int mf = 0; mf < 4; ++mf)
#pragma unroll
            for (int nf = 0; nf < 2; ++nf)
#pragma unroll
                for (int ks = 0; ks < 2; ++ks)
                    acc[mf][nf] = __builtin_amdgcn_mfma_f32_16x16x32_bf16(
                        fA[mf][ks], fB[nf][ks], acc[mf][nf], 0, 0, 0);
        __builtin_amdgcn_s_setprio(0);
        __builtin_amdgcn_s_barrier();

        // ---------- phase 2: quadrant (qm0, qn1) ----------
#pragma unroll
        for (int nf = 0; nf < 2; ++nf)
#pragma unroll
            for (int ks = 0; ks < 2; ++ks)
                fC[nf][ks] = *(const bf16x8*)(Bb + 4096 + nf * 2048 + co[nf & 1][ks]);
        if (t + 1 < NT) stage(A, tileM + 128, kn, nxt + 16384);
        __builtin_amdgcn_s_barrier();
        asm volatile("s_waitcnt lgkmcnt(0)" ::: "memory");
        __builtin_amdgcn_sched_barrier(0);
        __builtin_amdgcn_s_setprio(1);
#pragma unroll
        for (int mf = 0; mf < 4; ++mf)
#pragma unroll
            for (int nf = 0; nf < 2; ++nf)
#pragma unroll
                for (int ks = 0; ks < 2; ++ks)
                    acc[mf][2 + nf] = __builtin_amdgcn_mfma_f32_16x16x32_bf16(
                        fA[mf][ks], fC[nf][ks], acc[mf][2 + nf], 0, 0, 0);
        __builtin_amdgcn_s_setprio(0);
        __builtin_amdgcn_s_barrier();

        // ---------- phase 3: quadrant (qm1, qn1) ----------
#pragma unroll
        for (int mf = 0; mf < 4; ++mf)
#pragma unroll
            for (int ks = 0; ks < 2; ++ks)
                fD[mf][ks] = *(const bf16x8*)(Ab + 8192 + mf * 2048 + co[mf & 1][ks]);
        if (t + 1 < NT) stage(W, tileN, kn, nxt + 32768);
        __builtin_amdgcn_s_barrier();
        asm volatile("s_waitcnt lgkmcnt(0)" ::: "memory");
        __builtin_amdgcn_sched_barrier(0);
        __builtin_amdgcn_s_setprio(1);
#pragma unroll
        for (int mf = 0; mf < 4; ++mf)
#pragma unroll
            for (int nf = 0; nf < 2; ++nf)
#pragma unroll
                for (int ks = 0; ks < 2; ++ks)
                    acc[4 + mf][2 + nf] = __builtin_amdgcn_mfma_f32_16x16x32_bf16(
                        fD[mf][ks], fC[nf][ks], acc[4 + mf][2 + nf], 0, 0, 0);
        __builtin_amdgcn_s_setprio(0);
        __builtin_amdgcn_s_barrier();

        // ---------- phase 4: quadrant (qm1, qn0) ----------
        if (t + 1 < NT) stage(W, tileN + 128, kn, nxt + 49152);
        __builtin_amdgcn_s_barrier();
        __builtin_amdgcn_sched_barrier(0);
        __builtin_amdgcn_s_setprio(1);
#pragma unroll
        for (int mf = 0; mf < 4; ++mf)
#pragma unroll
            for (int nf = 0; nf < 2; ++nf)
#pragma unroll
                for (int ks = 0; ks < 2; ++ks)
                    acc[4 + mf][nf] = __builtin_amdgcn_mfma_f32_16x16x32_bf16(
                        fD[mf][ks], fB[nf][ks], acc[4 + mf][nf], 0, 0, 0);
        __builtin_amdgcn_s_setprio(0);
        if (t + 1 < NT) {
            asm volatile("s_waitcnt vmcnt(0)" ::: "memory");   // loads 1-4 phases old
        }
        __builtin_amdgcn_s_barrier();
    }

    // ---- epilogue: acc[mi][gate][v], all in registers. ----
    // 16x16 C/D map: col = lane&15 (= hl), row = quad*4 + v.
    const int hidx = (tileN >> 2) + wn * 16 + l15;   // global h in [0,1024)
    const float bi  = bx[hidx]        + bh[hidx];
    const float bff = bx[1024 + hidx] + bh[1024 + hidx];
    const float bo  = bx[2048 + hidx] + bh[2048 + hidx];
    const float bc  = bx[3072 + hidx] + bh[3072 + hidx];

#pragma unroll
    for (int mi = 0; mi < 8; ++mi) {
#pragma unroll
        for (int v = 0; v < 4; ++v) {
            int m = wm * 128 + mi * 16 + quad * 4 + v;
            size_t goff = (size_t)(tileM + m) * 1024 + hidx;
            float gi = acc[mi][0][v] + bi;
            float gf = acc[mi][1][v] + bff;
            float go = acc[mi][2][v] + bo;
            float gc = acc[mi][3][v] + bc;
            float c1v = c1[goff];
            float ii = sigmoidf_fast(gi);
            float ff = sigmoidf_fast(gf);
            float oo = sigmoidf_fast(go);
            float cb_ = tanhf_fast(gc);
            float cc = sigmoidf_fast(ff * c1v + ii * cb_);   // reference quirk
            float hn = tanhf_fast(cc) * oo;
            out[goff] = hn;
            out[8388608 + goff] = cc;
        }
    }
}

extern "C" void kernel_launch(void* const* d_in, const int* in_sizes, int n_in,
                              void* d_out, int out_size, void* d_ws, size_t ws_size,
                              hipStream_t stream) {
    const float* x  = (const float*)d_in[0];
    const float* h  = (const float*)d_in[1];
    const float* c1 = (const float*)d_in[2];
    const float* Wx = (const float*)d_in[3];
    const float* bx = (const float*)d_in[4];
    const float* Wh = (const float*)d_in[5];
    const float* bh = (const float*)d_in[6];
    float* out = (float*)d_out;

    char* ws = (char*)d_ws;
    unsigned short* Abf = (unsigned short*)(ws);                // 33,554,432 B
    unsigned short* Wbf = (unsigned short*)(ws + 33554432);     // 16,777,216 B

    prep_cat<<<12288, 256, 0, stream>>>(x, h, Wx, Wh, Abf, Wbf);
    gemm_lstm<<<512, 512, 0, stream>>>(Abf, Wbf, bx, bh, c1, out);
}